// Round 11
// baseline (578.595 us; speedup 1.0000x reference)
//
#include <hip/hip_runtime.h>

typedef unsigned short u16;
using short8_t  = __attribute__((ext_vector_type(8)))  short;
using float16_t = __attribute__((ext_vector_type(16))) float;
using float2v   = __attribute__((ext_vector_type(2)))  float;

#define NKT 260          // K-steps of 16: K = 64*64 + 64 = 4160
#define DEG_CAP 32

__device__ __forceinline__ float bf2f(u16 b) { return __uint_as_float(((unsigned)b) << 16); }
__device__ __forceinline__ u16 f2bf(float f) {
  unsigned u = __float_as_uint(f);
  return (u16)((u + 0x7fffu + ((u >> 16) & 1u)) >> 16);   // RNE
}

union U8 { short8_t s; uint4 v; unsigned u[4]; };

// z = (h * x) truncated to bf16, unpack fused. Bit-identical to prior rounds.
__device__ __forceinline__ short8_t scale8r(U8 xr, float2v h2) {
  U8 out;
  #pragma unroll
  for (int p = 0; p < 4; ++p) {
    float2v r;
    r[0] = __uint_as_float(xr.u[p] << 16);
    r[1] = __uint_as_float(xr.u[p] & 0xffff0000u);
    r = r * h2;
    out.u[p] = __builtin_amdgcn_perm(__float_as_uint(r[1]), __float_as_uint(r[0]), 0x07060302);
  }
  return out.s;
}

// ---------------- fused setup: all four relu(X @ W + b) + cnt zero-fill ----------------
template<int IN>
__device__ __forceinline__ void affine_body(
    const float* __restrict__ Xin, const float* __restrict__ W, const float* __restrict__ Bv,
    u16* __restrict__ Xout, int N, int gid)
{
  int n = gid >> 6, o = gid & 63;
  if (n >= N) return;
  float acc = Bv[o];
  #pragma unroll
  for (int i = 0; i < IN; ++i)
    acc = fmaf(Xin[n * IN + i], W[i * 64 + o], acc);
  Xout[gid] = f2bf(fmaxf(acc, 0.f));
}

__global__ __launch_bounds__(256) void affine_all_kernel(
    const float* __restrict__ gx, const float* __restrict__ l0w, const float* __restrict__ l0b, u16* __restrict__ xg,
    const float* __restrict__ lgx, const float* __restrict__ llw, const float* __restrict__ llb, u16* __restrict__ xl,
    const float* __restrict__ gea, const float* __restrict__ gw1, const float* __restrict__ gb1, u16* __restrict__ hg,
    const float* __restrict__ lea, const float* __restrict__ lw1, const float* __restrict__ lb1, u16* __restrict__ hl,
    int B0, int B1, int B2, int B3, int NG, int NLG, int EG, int ELG,
    int* __restrict__ zero_ptr, int NZ)
{
  int b = blockIdx.x, t = threadIdx.x;
  if (b < B0)       affine_body<20>(gx, l0w, l0b, xg, NG, b * 256 + t);
  else if (b < B1)  affine_body<5>(lgx, llw, llb, xl, NLG, (b - B0) * 256 + t);
  else if (b < B2)  affine_body<4>(gea, gw1, gb1, hg, EG, (b - B1) * 256 + t);
  else if (b < B3)  affine_body<1>(lea, lw1, lb1, hl, ELG, (b - B2) * 256 + t);
  else {            // cnt zero-fill (replaces hipMemsetAsync; completes before hist dispatch)
    int idx = (b - B3) * 256 + t;
    if (idx < NZ) zero_ptr[idx] = 0;
  }
}

// ---------------- fused packing: B_ext (both) + root (both) ----------------
__device__ __forceinline__ void bpack_body(
    const float* __restrict__ w2, const float* __restrict__ b2, u16* __restrict__ Bp, int gid)
{
  if (gid >= NKT * 128) return;
  int lane = gid & 63;
  int nt = (gid >> 6) & 1;
  int kt = gid >> 7;
  int o = nt * 32 + (lane & 31);
  int kbase = kt * 16 + (lane >> 5) * 8;
  u16 vals[8];
  #pragma unroll
  for (int j = 0; j < 8; ++j) {
    int k = kbase + j;
    vals[j] = f2bf((k < 4096) ? w2[(k >> 6) * 4096 + (k & 63) * 64 + o]
                              : b2[(k - 4096) * 64 + o]);
  }
  uint4 pack;
  pack.x = (unsigned)vals[0] | ((unsigned)vals[1] << 16);
  pack.y = (unsigned)vals[2] | ((unsigned)vals[3] << 16);
  pack.z = (unsigned)vals[4] | ((unsigned)vals[5] << 16);
  pack.w = (unsigned)vals[6] | ((unsigned)vals[7] << 16);
  *(uint4*)(Bp + (size_t)gid * 8) = pack;
}

__device__ __forceinline__ void rootpack_body(const float* __restrict__ root, u16* __restrict__ Rp, int gid)
{
  if (gid >= 512) return;
  int lane = gid & 63;
  int nt = (gid >> 6) & 1;
  int kt = gid >> 7;
  int o = nt * 32 + (lane & 31);
  int kbase = kt * 16 + (lane >> 5) * 8;
  u16 vals[8];
  #pragma unroll
  for (int j = 0; j < 8; ++j) vals[j] = f2bf(root[(kbase + j) * 64 + o]);
  uint4 pack;
  pack.x = (unsigned)vals[0] | ((unsigned)vals[1] << 16);
  pack.y = (unsigned)vals[2] | ((unsigned)vals[3] << 16);
  pack.z = (unsigned)vals[4] | ((unsigned)vals[5] << 16);
  pack.w = (unsigned)vals[6] | ((unsigned)vals[7] << 16);
  *(uint4*)(Rp + (size_t)gid * 8) = pack;
}

__global__ __launch_bounds__(256) void pack_all_kernel(
    const float* __restrict__ gw2, const float* __restrict__ gb2, u16* __restrict__ bpg,
    const float* __restrict__ lw2, const float* __restrict__ lb2, u16* __restrict__ bpl,
    const float* __restrict__ groot, u16* __restrict__ rpg,
    const float* __restrict__ lroot, u16* __restrict__ rpl)
{
  int b = blockIdx.x, t = threadIdx.x;
  if (b < 130)       bpack_body(gw2, gb2, bpg, b * 256 + t);
  else if (b < 260)  bpack_body(lw2, lb2, bpl, (b - 130) * 256 + t);
  else if (b < 262)  rootpack_body(groot, rpg, (b - 260) * 256 + t);
  else               rootpack_body(lroot, rpl, (b - 262) * 256 + t);
}

// ---------------- fused bucketed CSR ----------------
__device__ __forceinline__ void hist_body(
    const int* __restrict__ eidx, int* __restrict__ cnt, int* __restrict__ elist, int E, int e)
{
  if (e < E) {
    int tg = eidx[E + e];
    int pos = atomicAdd(cnt + tg, 1);
    if (pos < DEG_CAP) elist[(size_t)tg * DEG_CAP + pos] = e;
  }
}

__global__ __launch_bounds__(256) void hist_kernel(
    const int* __restrict__ eig, int* __restrict__ cg, int* __restrict__ elg, int Eg, int nbg,
    const int* __restrict__ eil, int* __restrict__ cl, int* __restrict__ ell, int El)
{
  int b = blockIdx.x, t = threadIdx.x;
  if (b < nbg) hist_body(eig, cg, elg, Eg, b * 256 + t);
  else         hist_body(eil, cl, ell, El, (b - nbg) * 256 + t);
}

// ---------------- msg = [h (x) x, x] @ B_ext — LDS ring, M=64/wave, 16KB chunks ----------------
// R8 config (best measured: 66us, MfmaUtil 40%). Untouched.
__global__ __launch_bounds__(256, 2) void msg_gemm_kernel(
    const u16* __restrict__ Xg, const u16* __restrict__ Hg, const u16* __restrict__ Bg,
    const int* __restrict__ eig, u16* __restrict__ Mg, int Eg, int nbg,
    const u16* __restrict__ Xl, const u16* __restrict__ Hl, const u16* __restrict__ Bl,
    const int* __restrict__ eil, u16* __restrict__ Ml, int El)
{
  __shared__ __align__(16) u16 sB[4][8192];   // 4 bufs x 16 KB ring

  const int b = blockIdx.x;
  const u16 *X, *Hh, *Bp; const int* eidx; u16* msg; int E, e0;
  if (b < nbg) { X = Xg; Hh = Hg; Bp = Bg; eidx = eig; msg = Mg; E = Eg; e0 = b * 256; }
  else         { X = Xl; Hh = Hl; Bp = Bl; eidx = eil; msg = Ml; E = El; e0 = (b - nbg) * 256; }

  const int t = threadIdx.x;
  const int lane = t & 63;
  const int wid = t >> 6;           // 4 waves x 64 edges = 256 edges/block
  const int ml = lane & 31;
  const int q  = lane >> 5;

  // stage chunks 0..2 immediately (12 DMAs) — overlap the x/h prologue gathers
  #pragma unroll
  for (int c0 = 0; c0 < 3; ++c0) {
    const u16* src = Bp + (size_t)c0 * 8192 + (size_t)wid * 2048 + (size_t)lane * 8;
    u16* dst = &sB[c0][wid * 2048];
    #pragma unroll
    for (int d = 0; d < 4; ++d)
      __builtin_amdgcn_global_load_lds((const __attribute__((address_space(1))) void*)(src + d * 512),
                                       (__attribute__((address_space(3))) void*)(dst + d * 512), 16, 0, 0);
  }

  const int ea  = e0 + wid * 64 + ml;       // tile0 row
  const int eb  = ea + 32;                  // tile1 row
  const int eac = ea < E ? ea : E - 1;
  const int ebc = eb < E ? eb : E - 1;
  const int sa  = eidx[eac], sb = eidx[ebc];

  // x raw bf16 (unpack fused into scale8r): 16 VGPR per tile
  U8 xra[4], xrb[4];
  {
    const u16* xpa = X + (size_t)sa * 64 + q * 8;
    const u16* xpb = X + (size_t)sb * 64 + q * 8;
    #pragma unroll
    for (int s = 0; s < 4; ++s) {
      xra[s].v = *(const uint4*)(xpa + s * 16);
      xrb[s].v = *(const uint4*)(xpb + s * 16);
    }
  }

  // h row streams (both tiles): one uint4 (8 h elems) per group of 4 chunks
  const uint4* ha4 = (const uint4*)(Hh + (size_t)eac * 64);
  const uint4* hb4 = (const uint4*)(Hh + (size_t)ebc * 64);
  uint4 hc0 = ha4[0], hn0 = ha4[1];
  uint4 hc1 = hb4[0], hn1 = hb4[1];

  float16_t acc00, acc01, acc10, acc11;
  #pragma unroll
  for (int i = 0; i < 16; ++i) { acc00[i] = 0.f; acc01[i] = 0.f; acc10[i] = 0.f; acc11[i] = 0.f; }

  // running DMA source pointer (chunk 3 first); bumped +8192 u16 per chunk
  const u16* bsrc = Bp + (size_t)3 * 8192 + (size_t)wid * 2048 + (size_t)lane * 8;

  const short8_t* sb8 = (const short8_t*)&sB[0][0];   // 16B-element view of the ring

  // prologue handoff: drain everything once, then one barrier. Loop never drains again.
  asm volatile("s_waitcnt vmcnt(0)" ::: "memory");
  __builtin_amdgcn_sched_barrier(0);
  __builtin_amdgcn_s_barrier();

  for (int g = 0; g < 8; ++g) {     // group = 4 chunks = 32 kt; hcur word cc -> 2 h-scalars
    #pragma unroll
    for (int cc = 0; cc < 4; ++cc) {
      {   // issue stage(c+3) into ring slot (cc+3)&3 — garbage chunks 33/34 land in Bp slack
        #pragma unroll
        for (int d = 0; d < 4; ++d)
          __builtin_amdgcn_global_load_lds((const __attribute__((address_space(1))) void*)(bsrc + d * 512),
                                           (__attribute__((address_space(3))) void*)(&sB[(cc + 3) & 3][wid * 2048] + d * 512), 16, 0, 0);
        bsrc += 8192;
      }
      unsigned w0 = ((const unsigned*)&hc0)[cc];                 // static index
      unsigned w1 = ((const unsigned*)&hc1)[cc];
      const int sbase = (cc & 3) * 1024;               // short8 index of ring slot (16KB = 1024 short8)
      #pragma unroll
      for (int hh = 0; hh < 2; ++hh) {                 // h-scalar within word: lo then hi
        float2v h20, h21;
        h20[0] = h20[1] = bf2f((u16)(hh ? (w0 >> 16) : (w0 & 0xffffu)));
        h21[0] = h21[1] = bf2f((u16)(hh ? (w1 >> 16) : (w1 & 0xffffu)));
        #pragma unroll
        for (int tt = 0; tt < 4; ++tt) {               // kt = 8c + 4hh + tt
          short8_t b0 = sb8[sbase + (hh * 4 + tt) * 128 + lane];
          short8_t b1 = sb8[sbase + (hh * 4 + tt) * 128 + 64 + lane];
          short8_t a0 = scale8r(xra[tt], h20);
          short8_t a1 = scale8r(xrb[tt], h21);
          acc00 = __builtin_amdgcn_mfma_f32_32x32x16_bf16(a0, b0, acc00, 0, 0, 0);
          acc01 = __builtin_amdgcn_mfma_f32_32x32x16_bf16(a0, b1, acc01, 0, 0, 0);
          acc10 = __builtin_amdgcn_mfma_f32_32x32x16_bf16(a1, b0, acc10, 0, 0, 0);
          acc11 = __builtin_amdgcn_mfma_f32_32x32x16_bf16(a1, b1, acc11, 0, 0, 0);
        }
      }
      // counted handoff: my ds_reads done (free), my stage(c+1) retired; c+2/c+3 in flight
      asm volatile("s_waitcnt lgkmcnt(0)" ::: "memory");
      asm volatile("s_waitcnt vmcnt(8)" ::: "memory");
      __builtin_amdgcn_sched_barrier(0);
      __builtin_amdgcn_s_barrier();
    }
    hc0 = hn0; hc1 = hn1;
    if (g < 6) { hn0 = ha4[g + 2]; hn1 = hb4[g + 2]; }
  }

  // tail: chunk 32 = kt 256..259 (b2 bias rows), A = x exactly (hs=1.0), ring slot 0
  {
    float2v h2; h2[0] = 1.0f; h2[1] = 1.0f;
    #pragma unroll
    for (int tt = 0; tt < 4; ++tt) {
      short8_t b0 = sb8[tt * 128 + lane];
      short8_t b1 = sb8[tt * 128 + 64 + lane];
      short8_t a0 = scale8r(xra[tt], h2);
      short8_t a1 = scale8r(xrb[tt], h2);
      acc00 = __builtin_amdgcn_mfma_f32_32x32x16_bf16(a0, b0, acc00, 0, 0, 0);
      acc01 = __builtin_amdgcn_mfma_f32_32x32x16_bf16(a0, b1, acc01, 0, 0, 0);
      acc10 = __builtin_amdgcn_mfma_f32_32x32x16_bf16(a1, b0, acc10, 0, 0, 0);
      acc11 = __builtin_amdgcn_mfma_f32_32x32x16_bf16(a1, b1, acc11, 0, 0, 0);
    }
  }

  // epilogue: C/D layout col=lane&31, row=(reg&3)+8*(reg>>2)+4*q; bf16 stores, both tiles
  #pragma unroll
  for (int reg = 0; reg < 16; ++reg) {
    int row = (reg & 3) + 8 * (reg >> 2) + 4 * q;
    int e1 = e0 + wid * 64 + row;
    int e2 = e1 + 32;
    if (e1 < E) {
      msg[(size_t)e1 * 64 + ml]      = f2bf(acc00[reg]);
      msg[(size_t)e1 * 64 + 32 + ml] = f2bf(acc01[reg]);
    }
    if (e2 < E) {
      msg[(size_t)e2 * 64 + ml]      = f2bf(acc10[reg]);
      msg[(size_t)e2 * 64 + 32 + ml] = f2bf(acc11[reg]);
    }
  }
}

// ---------------- x_new = relu(x @ root + gather_mean(msg) + bias) — MFMA, fused ----------------
__global__ __launch_bounds__(256, 4) void update_kernel(
    const u16* __restrict__ Xig, const u16* __restrict__ Mgg, const int* __restrict__ cg,
    const int* __restrict__ elg, const u16* __restrict__ rpg, const float* __restrict__ bg,
    u16* __restrict__ Xog, int Ng, int nbg,
    const u16* __restrict__ Xil, const u16* __restrict__ Mgl, const int* __restrict__ cl,
    const int* __restrict__ ell, const u16* __restrict__ rpl, const float* __restrict__ bl,
    u16* __restrict__ Xol, int Nl)
{
  const int b = blockIdx.x;
  const u16 *Xin, *rootp, *msg; const float *bias; const int *cnt, *elist;
  u16* Xout; int N, n0;
  if (b < nbg) { Xin=Xig; msg=Mgg; cnt=cg; elist=elg; rootp=rpg; bias=bg; Xout=Xog; N=Ng; n0=b*128; }
  else         { Xin=Xil; msg=Mgl; cnt=cl; elist=ell; rootp=rpl; bias=bl; Xout=Xol; N=Nl; n0=(b-nbg)*128; }

  const int t = threadIdx.x;
  const int lane = t & 63;
  const int wid = t >> 6;
  const int ml = lane & 31;
  const int q  = lane >> 5;
  const int nbase = n0 + wid * 32;

  const int na = nbase + ml;
  const int nac = na < N ? na : N - 1;

  U8 xr[4];
  {
    const u16* xp = Xin + (size_t)nac * 64 + q * 8;
    #pragma unroll
    for (int s = 0; s < 4; ++s) xr[s].v = *(const uint4*)(xp + s * 16);
  }
  U8 rp[8];
  {
    const uint4* rpv = (const uint4*)rootp;
    #pragma unroll
    for (int i = 0; i < 8; ++i) rp[i].v = rpv[i * 64 + lane];
  }
  const float bias0 = bias[ml], bias1 = bias[32 + ml];

  float16_t acc0, acc1;
  #pragma unroll
  for (int i = 0; i < 16; ++i) { acc0[i] = 0.f; acc1[i] = 0.f; }
  #pragma unroll
  for (int kt = 0; kt < 4; ++kt) {
    acc0 = __builtin_amdgcn_mfma_f32_32x32x16_bf16(xr[kt].s, rp[kt * 2 + 0].s, acc0, 0, 0, 0);
    acc1 = __builtin_amdgcn_mfma_f32_32x32x16_bf16(xr[kt].s, rp[kt * 2 + 1].s, acc1, 0, 0, 0);
  }

  #pragma unroll
  for (int reg = 0; reg < 16; ++reg) {
    int row = (reg & 3) + 8 * (reg >> 2) + 4 * q;
    int nn = nbase + row;
    if (nn < N) {
      int c = cnt[nn];
      int cc = c < DEG_CAP ? c : DEG_CAP;
      const int* ep = elist + (size_t)nn * DEG_CAP;
      float a0 = 0.f, a1 = 0.f;
      int j = 0;
      for (; j + 4 <= cc; j += 4) {      // de-serialized: 4 elist + 8 msg loads in flight
        int e0i = ep[j], e1i = ep[j + 1], e2i = ep[j + 2], e3i = ep[j + 3];
        u16 m00 = msg[(size_t)e0i * 64 + ml], m01 = msg[(size_t)e0i * 64 + 32 + ml];
        u16 m10 = msg[(size_t)e1i * 64 + ml], m11 = msg[(size_t)e1i * 64 + 32 + ml];
        u16 m20 = msg[(size_t)e2i * 64 + ml], m21 = msg[(size_t)e2i * 64 + 32 + ml];
        u16 m30 = msg[(size_t)e3i * 64 + ml], m31 = msg[(size_t)e3i * 64 + 32 + ml];
        a0 += bf2f(m00) + bf2f(m10) + bf2f(m20) + bf2f(m30);
        a1 += bf2f(m01) + bf2f(m11) + bf2f(m21) + bf2f(m31);
      }
      for (; j < cc; ++j) {
        int e = ep[j];
        a0 += bf2f(msg[(size_t)e * 64 + ml]);
        a1 += bf2f(msg[(size_t)e * 64 + 32 + ml]);
      }
      float rc = (c > 1) ? (1.0f / (float)c) : 1.0f;
      float o0 = fmaxf(acc0[reg] + a0 * rc + bias0, 0.f);
      float o1 = fmaxf(acc1[reg] + a1 * rc + bias1, 0.f);
      Xout[(size_t)nn * 64 + ml]      = f2bf(o0);
      Xout[(size_t)nn * 64 + 32 + ml] = f2bf(o1);
    }
  }
}

// ---------------- pool: per-block partials + head-weight L2 prefetch tail ----------------
__device__ __forceinline__ void pool_body(const u16* __restrict__ X, float* __restrict__ part,
                                          int nchunks, int bid, int t)
{
  __shared__ float red[64];
  if (t < 64) red[t] = 0.f;
  __syncthreads();
  int gid = bid * 256 + t;
  float s[8];
  #pragma unroll
  for (int j = 0; j < 8; ++j) s[j] = 0.f;
  for (int i = gid; i < nchunks; i += 256 * 256) {
    uint4 v = ((const uint4*)X)[i];
    s[0] += bf2f((u16)(v.x & 0xffffu)); s[1] += bf2f((u16)(v.x >> 16));
    s[2] += bf2f((u16)(v.y & 0xffffu)); s[3] += bf2f((u16)(v.y >> 16));
    s[4] += bf2f((u16)(v.z & 0xffffu)); s[5] += bf2f((u16)(v.z >> 16));
    s[6] += bf2f((u16)(v.w & 0xffffu)); s[7] += bf2f((u16)(v.w >> 16));
  }
  int cg = (gid & 7) * 8;
  #pragma unroll
  for (int j = 0; j < 8; ++j) atomicAdd(red + cg + j, s[j]);
  __syncthreads();
  if (t < 64) part[bid * 64 + t] = red[t];
}

// prefetch: 64 blocks (8 chunk-groups x 8 XCD-round-robin) touch bott_w + l1w so each
// XCD's L2 (and the L3) is warm before head_kernel. Reads kept live via asm.
__device__ __forceinline__ void prefetch_body(const float* __restrict__ bw,
                                              const float* __restrict__ l1w, int pb, int t)
{
  const int chunk = pb >> 3;              // 0..7 (same chunk hits all 8 XCDs across pb%8)
  float acc = 0.f;
  {   // bott_w: 131*384 = 50304 floats = 12576 float4; chunk = 1572 f4
    const float4* p = (const float4*)bw;
    for (int i = chunk * 1572 + t; i < (chunk + 1) * 1572; i += 256) {
      float4 v = p[i];
      acc += v.x + v.y + v.z + v.w;
    }
  }
  {   // l1w: 384*384 = 147456 floats = 36864 float4; chunk = 4608 f4
    const float4* p = (const float4*)l1w;
    for (int i = chunk * 4608 + t; i < (chunk + 1) * 4608; i += 256) {
      float4 v = p[i];
      acc += v.x + v.y + v.z + v.w;
    }
  }
  asm volatile("" :: "v"(acc));           // keep loads live (rule #17)
}

__global__ __launch_bounds__(256) void pool_kernel(
    const u16* __restrict__ Xg, float* __restrict__ pg_part, int ncg,
    const u16* __restrict__ Xl, float* __restrict__ pl_part, int ncl,
    const float* __restrict__ bw, const float* __restrict__ l1w)
{
  int b = blockIdx.x, t = threadIdx.x;
  if (b < 256)      pool_body(Xg, pg_part, ncg, b, t);
  else if (b < 512) pool_body(Xl, pl_part, ncl, b - 256, t);
  else              prefetch_body(bw, l1w, b - 512, t);
}

// ---------------- fused head, reg-cached weights: 768 thr, 2 threads/column ----------------
// R10 post-mortem: head time = L2 lines x latency / (waves x ~6.3 lines-in-flight);
// 3.9 MB L2 traffic (l1w re-read 6x) at 12 waves -> 67us model == 71us measured.
// Fix: l1w is identical across layers -> cache 128 of each thread's 192 weights in
// VGPRs (loaded once; ~165 VGPR fits 12-wave block at 512-regs/SIMD pool), stream the
// other 64/layer. L2 traffic 3.9 -> ~1.3 MB. Cold-HBM first touch removed by the
// pool-tail prefetch. All f32; reassociation << 0.63 threshold.
__global__ __launch_bounds__(768) void head_kernel(
    const float* __restrict__ ppg, const float* __restrict__ ppl, const float* __restrict__ adduct,
    const float* __restrict__ bw, const float* __restrict__ bb,
    const float* __restrict__ l1w, const float* __restrict__ l1b,
    const float* __restrict__ l2w, const float* __restrict__ l2b,
    float* __restrict__ out)
{
  __shared__ float hv[132];
  __shared__ float u[384];
  __shared__ float ph[2][384];
  __shared__ float wred[6];
  const int t = threadIdx.x;
  const int col  = (t < 384) ? t : t - 384;
  const int half = (t < 384) ? 0 : 1;
  const int i0 = half * 192;

  // register-cache first 128 of this thread's 192 l1w rows (same for all 6 layers).
  // Issued first: load latency overlaps the pool-reduce + bott phases.
  float wc[128];
  #pragma unroll
  for (int j = 0; j < 128; ++j)
    wc[j] = l1w[(i0 + j) * 384 + col];

  if (t < 132) hv[t] = 0.f;
  __syncthreads();

  // pool partial reduction: (cg,br) owned by 24 threads, each sums b strided by 24
  {
    const int cg = t & 15, br = (t >> 4) & 1, tb = t >> 5;   // tb in 0..23
    const float* pp = br ? ppl : ppg;
    float a0 = 0.f, a1 = 0.f, a2 = 0.f, a3 = 0.f;
    for (int b = tb; b < 256; b += 24) {
      const float4 v = *(const float4*)(pp + b * 64 + cg * 4);
      a0 += v.x; a1 += v.y; a2 += v.z; a3 += v.w;
    }
    float* dst = hv + br * 64 + cg * 4;
    atomicAdd(dst + 0, a0); atomicAdd(dst + 1, a1);
    atomicAdd(dst + 2, a2); atomicAdd(dst + 3, a3);
    if (t < 3) hv[128 + t] = adduct[t];    // disjoint from atomic targets (cols 0..127)
  }
  __syncthreads();

  // bott: u = relu(bb + hv[0:131] @ bw), split i-range per half (streamed, L2-warm)
  {
    const int b0 = half ? 66 : 0;
    const int b1 = half ? 131 : 66;
    float pa[8];
    #pragma unroll
    for (int j = 0; j < 8; ++j) pa[j] = 0.f;
    int i = b0;
    for (; i + 8 <= b1; i += 8) {
      #pragma unroll
      for (int j = 0; j < 8; ++j)
        pa[j] = fmaf(hv[i + j], bw[(i + j) * 384 + col], pa[j]);
    }
    for (; i < b1; ++i) pa[0] = fmaf(hv[i], bw[i * 384 + col], pa[0]);
    float s = ((pa[0] + pa[1]) + (pa[2] + pa[3])) + ((pa[4] + pa[5]) + (pa[6] + pa[7]));
    ph[half][col] = s;
  }
  __syncthreads();
  if (t < 384) u[t] = fmaxf(bb[t] + ph[0][t] + ph[1][t], 0.f);
  __syncthreads();

  // 6x lin1: 128 cached-weight fmas (VALU) + 64 streamed (8 indep chains)
  for (int L = 0; L < 6; ++L) {
    float pa[8];
    #pragma unroll
    for (int j = 0; j < 8; ++j) pa[j] = 0.f;
    #pragma unroll
    for (int j = 0; j < 128; ++j)
      pa[j & 7] = fmaf(u[i0 + j], wc[j], pa[j & 7]);
    float pb[8];
    #pragma unroll
    for (int j = 0; j < 8; ++j) pb[j] = 0.f;
    #pragma unroll 1
    for (int jb = 128; jb < 192; jb += 8) {
      #pragma unroll
      for (int k = 0; k < 8; ++k)
        pb[k] = fmaf(u[i0 + jb + k], l1w[(i0 + jb + k) * 384 + col], pb[k]);
    }
    float s = (((pa[0] + pa[1]) + (pa[2] + pa[3])) + ((pa[4] + pa[5]) + (pa[6] + pa[7])))
            + (((pb[0] + pb[1]) + (pb[2] + pb[3])) + ((pb[4] + pb[5]) + (pb[6] + pb[7])));
    ph[half][col] = s;
    __syncthreads();
    if (t < 384) u[t] = fmaxf(l1b[t] + ph[0][t] + ph[1][t], 0.f);
    __syncthreads();
  }

  // final: u @ l2w + l2b -> scalar (waves 0-5 only; waves 6-11 uniformly idle)
  {
    if (t < 384) {
      float p = u[t] * l2w[t];
      #pragma unroll
      for (int off = 32; off > 0; off >>= 1) p += __shfl_down(p, off);
      if ((t & 63) == 0) wred[t >> 6] = p;
    }
    __syncthreads();
    if (t == 0) {
      float s = l2b[0];
      #pragma unroll
      for (int i = 0; i < 6; ++i) s += wred[i];
      out[0] = s;
    }
  }
}

extern "C" void kernel_launch(void* const* d_in, const int* in_sizes, int n_in,
                              void* d_out, int out_size, void* d_ws, size_t ws_size,
                              hipStream_t stream)
{
  const int NG = 30000, EG = 60000, NLG = 60000, ELG = 60000;

  const float* gx      = (const float*)d_in[0];
  const int*   g_ei    = (const int*)  d_in[1];
  const float* g_ea    = (const float*)d_in[2];
  const float* lgx     = (const float*)d_in[3];
  const int*   lg_ei   = (const int*)  d_in[4];
  const float* lg_ea   = (const float*)d_in[5];
  const float* adduct  = (const float*)d_in[6];
  const float* lin0_w  = (const float*)d_in[7];
  const float* lin0_b  = (const float*)d_in[8];
  const float* g_w1    = (const float*)d_in[9];
  const float* g_b1    = (const float*)d_in[10];
  const float* g_w2    = (const float*)d_in[11];
  const float* g_b2    = (const float*)d_in[12];
  const float* g_root  = (const float*)d_in[13];
  const float* g_bias  = (const float*)d_in[14];
  const float* l0lg_w  = (const float*)d_in[15];
  const float* l0lg_b  = (const float*)d_in[16];
  const float* lg_w1   = (const float*)d_in[17];
  const float* lg_b1   = (const float*)d_in[18];
  const float* lg_w2   = (const float*)d_in[19];
  const float* lg_b2   = (const float*)d_in[20];
  const float* lg_root = (const float*)d_in[21];
  const float* lg_bias = (const float*)d_in[22];
  const float* bott_w  = (const float*)d_in[23];
  const float* bott_b  = (const float*)d_in[24];
  const float* lin1_w  = (const float*)d_in[25];
  const float* lin1_b  = (const float*)d_in[26];
  const float* lin2_w  = (const float*)d_in[27];
  const float* lin2_b  = (const float*)d_in[28];

  char* p = (char*)d_ws;
  auto alloc = [&](size_t bytes) { char* r = p; p += (bytes + 255) & ~(size_t)255; return r; };
  u16*   xg_a   = (u16*)  alloc((size_t)NG  * 64 * 2);
  u16*   xg_b   = (u16*)  alloc((size_t)NG  * 64 * 2);
  u16*   xl_a   = (u16*)  alloc((size_t)NLG * 64 * 2);
  u16*   xl_b   = (u16*)  alloc((size_t)NLG * 64 * 2);
  u16*   h_g    = (u16*)  alloc((size_t)EG  * 64 * 2);
  u16*   h_l    = (u16*)  alloc((size_t)ELG * 64 * 2);
  u16*   bp_g   = (u16*)  alloc((size_t)NKT * 128 * 8 * 2 + 49152);  // slack: 16KB chunks stage up to chunk 34
  u16*   bp_l   = (u16*)  alloc((size_t)NKT * 128 * 8 * 2 + 49152);
  u16*   rp_g   = (u16*)  alloc(512 * 8 * 2);
  u16*   rp_l   = (u16*)  alloc(512 * 8 * 2);
  u16*   msg_g  = (u16*)  alloc((size_t)EG  * 64 * 2);   // bf16 msg
  u16*   msg_l  = (u16*)  alloc((size_t)ELG * 64 * 2);
  int*   cnt_g  = (int*)  alloc((size_t)NG  * 4);   // cnt_g/cnt_l adjacent: single zero-fill span
  int*   cnt_l  = (int*)  alloc((size_t)NLG * 4);
  int*   el_g   = (int*)  alloc((size_t)NG  * DEG_CAP * 4);
  int*   el_l   = (int*)  alloc((size_t)NLG * DEG_CAP * 4);
  float* pp_g   = (float*)alloc(256 * 64 * 4);      // pool partials
  float* pp_l   = (float*)alloc(256 * 64 * 4);

  // ---- setup (cnt zero-fill folded into affine_all; no memsets) ----
  const int B0 = NG * 64 / 256, B1 = B0 + NLG * 64 / 256, B2 = B1 + EG * 64 / 256;
  const int B3 = B2 + ELG * 64 / 256;
  const int NZ = (int)(((size_t)((char*)cnt_l - (char*)cnt_g)) / 4) + NLG;  // span incl. align pad
  const int zb = (NZ + 255) / 256;
  affine_all_kernel<<<B3 + zb, 256, 0, stream>>>(
      gx, lin0_w, lin0_b, xg_a, lgx, l0lg_w, l0lg_b, xl_a,
      g_ea, g_w1, g_b1, h_g, lg_ea, lg_w1, lg_b1, h_l,
      B0, B1, B2, B3, NG, NLG, EG, ELG, cnt_g, NZ);
  pack_all_kernel<<<264, 256, 0, stream>>>(g_w2, g_b2, bp_g, lg_w2, lg_b2, bp_l,
                                           g_root, rp_g, lg_root, rp_l);
  const int nhg = (EG + 255) / 256, nhl = (ELG + 255) / 256;
  hist_kernel<<<nhg + nhl, 256, 0, stream>>>(g_ei, cnt_g, el_g, EG, nhg, lg_ei, cnt_l, el_l, ELG);

  // ---- fused 3-iteration loop (256 edges/block, 4 waves x 64 edges, 16KB-chunk LDS ring) ----
  const int nbg_m = (EG + 255) / 256, nbl_m = (ELG + 255) / 256;
  const int nbg_u = (NG + 127) / 128, nbl_u = (NLG + 127) / 128;
  u16 *xgc = xg_a, *xgn = xg_b, *xlc = xl_a, *xln = xl_b;
  for (int it = 0; it < 3; ++it) {
    msg_gemm_kernel<<<nbg_m + nbl_m, 256, 0, stream>>>(
        xgc, h_g, bp_g, g_ei, msg_g, EG, nbg_m,
        xlc, h_l, bp_l, lg_ei, msg_l, ELG);
    update_kernel<<<nbg_u + nbl_u, 256, 0, stream>>>(
        xgc, msg_g, cnt_g, el_g, rp_g, g_bias, xgn, NG, nbg_u,
        xlc, msg_l, cnt_l, el_l, rp_l, lg_bias, xln, NLG);
    u16* tmp = xgc; xgc = xgn; xgn = tmp;
    tmp = xlc; xlc = xln; xln = tmp;
  }

  pool_kernel<<<576, 256, 0, stream>>>(xgc, pp_g, NG * 8, xlc, pp_l, NLG * 8,
                                       bott_w, lin1_w);

  head_kernel<<<1, 768, 0, stream>>>(pp_g, pp_l, adduct,
                                     bott_w, bott_b, lin1_w, lin1_b, lin2_w, lin2_b,
                                     (float*)d_out);
}

// Round 12
// 487.257 us; speedup vs baseline: 1.1875x; 1.1875x over previous
//
#include <hip/hip_runtime.h>

typedef unsigned short u16;
using short8_t  = __attribute__((ext_vector_type(8)))  short;
using float16_t = __attribute__((ext_vector_type(16))) float;
using float2v   = __attribute__((ext_vector_type(2)))  float;

#define NKT 260          // K-steps of 16: K = 64*64 + 64 = 4160
#define DEG_CAP 32

__device__ __forceinline__ float bf2f(u16 b) { return __uint_as_float(((unsigned)b) << 16); }
__device__ __forceinline__ u16 f2bf(float f) {
  unsigned u = __float_as_uint(f);
  return (u16)((u + 0x7fffu + ((u >> 16) & 1u)) >> 16);   // RNE
}

union U8 { short8_t s; uint4 v; unsigned u[4]; };

// z = (h * x) truncated to bf16, unpack fused. Bit-identical to prior rounds.
__device__ __forceinline__ short8_t scale8r(U8 xr, float2v h2) {
  U8 out;
  #pragma unroll
  for (int p = 0; p < 4; ++p) {
    float2v r;
    r[0] = __uint_as_float(xr.u[p] << 16);
    r[1] = __uint_as_float(xr.u[p] & 0xffff0000u);
    r = r * h2;
    out.u[p] = __builtin_amdgcn_perm(__float_as_uint(r[1]), __float_as_uint(r[0]), 0x07060302);
  }
  return out.s;
}

// ---------------- fused setup: all four relu(X @ W + b) + cnt zero-fill ----------------
template<int IN>
__device__ __forceinline__ void affine_body(
    const float* __restrict__ Xin, const float* __restrict__ W, const float* __restrict__ Bv,
    u16* __restrict__ Xout, int N, int gid)
{
  int n = gid >> 6, o = gid & 63;
  if (n >= N) return;
  float acc = Bv[o];
  #pragma unroll
  for (int i = 0; i < IN; ++i)
    acc = fmaf(Xin[n * IN + i], W[i * 64 + o], acc);
  Xout[gid] = f2bf(fmaxf(acc, 0.f));
}

__global__ __launch_bounds__(256) void affine_all_kernel(
    const float* __restrict__ gx, const float* __restrict__ l0w, const float* __restrict__ l0b, u16* __restrict__ xg,
    const float* __restrict__ lgx, const float* __restrict__ llw, const float* __restrict__ llb, u16* __restrict__ xl,
    const float* __restrict__ gea, const float* __restrict__ gw1, const float* __restrict__ gb1, u16* __restrict__ hg,
    const float* __restrict__ lea, const float* __restrict__ lw1, const float* __restrict__ lb1, u16* __restrict__ hl,
    int B0, int B1, int B2, int B3, int NG, int NLG, int EG, int ELG,
    int* __restrict__ zero_ptr, int NZ)
{
  int b = blockIdx.x, t = threadIdx.x;
  if (b < B0)       affine_body<20>(gx, l0w, l0b, xg, NG, b * 256 + t);
  else if (b < B1)  affine_body<5>(lgx, llw, llb, xl, NLG, (b - B0) * 256 + t);
  else if (b < B2)  affine_body<4>(gea, gw1, gb1, hg, EG, (b - B1) * 256 + t);
  else if (b < B3)  affine_body<1>(lea, lw1, lb1, hl, ELG, (b - B2) * 256 + t);
  else {            // cnt zero-fill (replaces hipMemsetAsync; completes before hist dispatch)
    int idx = (b - B3) * 256 + t;
    if (idx < NZ) zero_ptr[idx] = 0;
  }
}

// ---------------- fused packing: B_ext (both) + root (both) ----------------
__device__ __forceinline__ void bpack_body(
    const float* __restrict__ w2, const float* __restrict__ b2, u16* __restrict__ Bp, int gid)
{
  if (gid >= NKT * 128) return;
  int lane = gid & 63;
  int nt = (gid >> 6) & 1;
  int kt = gid >> 7;
  int o = nt * 32 + (lane & 31);
  int kbase = kt * 16 + (lane >> 5) * 8;
  u16 vals[8];
  #pragma unroll
  for (int j = 0; j < 8; ++j) {
    int k = kbase + j;
    vals[j] = f2bf((k < 4096) ? w2[(k >> 6) * 4096 + (k & 63) * 64 + o]
                              : b2[(k - 4096) * 64 + o]);
  }
  uint4 pack;
  pack.x = (unsigned)vals[0] | ((unsigned)vals[1] << 16);
  pack.y = (unsigned)vals[2] | ((unsigned)vals[3] << 16);
  pack.z = (unsigned)vals[4] | ((unsigned)vals[5] << 16);
  pack.w = (unsigned)vals[6] | ((unsigned)vals[7] << 16);
  *(uint4*)(Bp + (size_t)gid * 8) = pack;
}

__device__ __forceinline__ void rootpack_body(const float* __restrict__ root, u16* __restrict__ Rp, int gid)
{
  if (gid >= 512) return;
  int lane = gid & 63;
  int nt = (gid >> 6) & 1;
  int kt = gid >> 7;
  int o = nt * 32 + (lane & 31);
  int kbase = kt * 16 + (lane >> 5) * 8;
  u16 vals[8];
  #pragma unroll
  for (int j = 0; j < 8; ++j) vals[j] = f2bf(root[(kbase + j) * 64 + o]);
  uint4 pack;
  pack.x = (unsigned)vals[0] | ((unsigned)vals[1] << 16);
  pack.y = (unsigned)vals[2] | ((unsigned)vals[3] << 16);
  pack.z = (unsigned)vals[4] | ((unsigned)vals[5] << 16);
  pack.w = (unsigned)vals[6] | ((unsigned)vals[7] << 16);
  *(uint4*)(Rp + (size_t)gid * 8) = pack;
}

__global__ __launch_bounds__(256) void pack_all_kernel(
    const float* __restrict__ gw2, const float* __restrict__ gb2, u16* __restrict__ bpg,
    const float* __restrict__ lw2, const float* __restrict__ lb2, u16* __restrict__ bpl,
    const float* __restrict__ groot, u16* __restrict__ rpg,
    const float* __restrict__ lroot, u16* __restrict__ rpl)
{
  int b = blockIdx.x, t = threadIdx.x;
  if (b < 130)       bpack_body(gw2, gb2, bpg, b * 256 + t);
  else if (b < 260)  bpack_body(lw2, lb2, bpl, (b - 130) * 256 + t);
  else if (b < 262)  rootpack_body(groot, rpg, (b - 260) * 256 + t);
  else               rootpack_body(lroot, rpl, (b - 262) * 256 + t);
}

// ---------------- fused bucketed CSR ----------------
__device__ __forceinline__ void hist_body(
    const int* __restrict__ eidx, int* __restrict__ cnt, int* __restrict__ elist, int E, int e)
{
  if (e < E) {
    int tg = eidx[E + e];
    int pos = atomicAdd(cnt + tg, 1);
    if (pos < DEG_CAP) elist[(size_t)tg * DEG_CAP + pos] = e;
  }
}

__global__ __launch_bounds__(256) void hist_kernel(
    const int* __restrict__ eig, int* __restrict__ cg, int* __restrict__ elg, int Eg, int nbg,
    const int* __restrict__ eil, int* __restrict__ cl, int* __restrict__ ell, int El)
{
  int b = blockIdx.x, t = threadIdx.x;
  if (b < nbg) hist_body(eig, cg, elg, Eg, b * 256 + t);
  else         hist_body(eil, cl, ell, El, (b - nbg) * 256 + t);
}

// ---------------- msg = [h (x) x, x] @ B_ext — LDS ring, M=64/wave, 16KB chunks ----------------
// R8 config (best measured: 66us, MfmaUtil 40%). Untouched.
__global__ __launch_bounds__(256, 2) void msg_gemm_kernel(
    const u16* __restrict__ Xg, const u16* __restrict__ Hg, const u16* __restrict__ Bg,
    const int* __restrict__ eig, u16* __restrict__ Mg, int Eg, int nbg,
    const u16* __restrict__ Xl, const u16* __restrict__ Hl, const u16* __restrict__ Bl,
    const int* __restrict__ eil, u16* __restrict__ Ml, int El)
{
  __shared__ __align__(16) u16 sB[4][8192];   // 4 bufs x 16 KB ring

  const int b = blockIdx.x;
  const u16 *X, *Hh, *Bp; const int* eidx; u16* msg; int E, e0;
  if (b < nbg) { X = Xg; Hh = Hg; Bp = Bg; eidx = eig; msg = Mg; E = Eg; e0 = b * 256; }
  else         { X = Xl; Hh = Hl; Bp = Bl; eidx = eil; msg = Ml; E = El; e0 = (b - nbg) * 256; }

  const int t = threadIdx.x;
  const int lane = t & 63;
  const int wid = t >> 6;           // 4 waves x 64 edges = 256 edges/block
  const int ml = lane & 31;
  const int q  = lane >> 5;

  // stage chunks 0..2 immediately (12 DMAs) — overlap the x/h prologue gathers
  #pragma unroll
  for (int c0 = 0; c0 < 3; ++c0) {
    const u16* src = Bp + (size_t)c0 * 8192 + (size_t)wid * 2048 + (size_t)lane * 8;
    u16* dst = &sB[c0][wid * 2048];
    #pragma unroll
    for (int d = 0; d < 4; ++d)
      __builtin_amdgcn_global_load_lds((const __attribute__((address_space(1))) void*)(src + d * 512),
                                       (__attribute__((address_space(3))) void*)(dst + d * 512), 16, 0, 0);
  }

  const int ea  = e0 + wid * 64 + ml;       // tile0 row
  const int eb  = ea + 32;                  // tile1 row
  const int eac = ea < E ? ea : E - 1;
  const int ebc = eb < E ? eb : E - 1;
  const int sa  = eidx[eac], sb = eidx[ebc];

  // x raw bf16 (unpack fused into scale8r): 16 VGPR per tile
  U8 xra[4], xrb[4];
  {
    const u16* xpa = X + (size_t)sa * 64 + q * 8;
    const u16* xpb = X + (size_t)sb * 64 + q * 8;
    #pragma unroll
    for (int s = 0; s < 4; ++s) {
      xra[s].v = *(const uint4*)(xpa + s * 16);
      xrb[s].v = *(const uint4*)(xpb + s * 16);
    }
  }

  // h row streams (both tiles): one uint4 (8 h elems) per group of 4 chunks
  const uint4* ha4 = (const uint4*)(Hh + (size_t)eac * 64);
  const uint4* hb4 = (const uint4*)(Hh + (size_t)ebc * 64);
  uint4 hc0 = ha4[0], hn0 = ha4[1];
  uint4 hc1 = hb4[0], hn1 = hb4[1];

  float16_t acc00, acc01, acc10, acc11;
  #pragma unroll
  for (int i = 0; i < 16; ++i) { acc00[i] = 0.f; acc01[i] = 0.f; acc10[i] = 0.f; acc11[i] = 0.f; }

  // running DMA source pointer (chunk 3 first); bumped +8192 u16 per chunk
  const u16* bsrc = Bp + (size_t)3 * 8192 + (size_t)wid * 2048 + (size_t)lane * 8;

  const short8_t* sb8 = (const short8_t*)&sB[0][0];   // 16B-element view of the ring

  // prologue handoff: drain everything once, then one barrier. Loop never drains again.
  asm volatile("s_waitcnt vmcnt(0)" ::: "memory");
  __builtin_amdgcn_sched_barrier(0);
  __builtin_amdgcn_s_barrier();

  for (int g = 0; g < 8; ++g) {     // group = 4 chunks = 32 kt; hcur word cc -> 2 h-scalars
    #pragma unroll
    for (int cc = 0; cc < 4; ++cc) {
      {   // issue stage(c+3) into ring slot (cc+3)&3 — garbage chunks 33/34 land in Bp slack
        #pragma unroll
        for (int d = 0; d < 4; ++d)
          __builtin_amdgcn_global_load_lds((const __attribute__((address_space(1))) void*)(bsrc + d * 512),
                                           (__attribute__((address_space(3))) void*)(&sB[(cc + 3) & 3][wid * 2048] + d * 512), 16, 0, 0);
        bsrc += 8192;
      }
      unsigned w0 = ((const unsigned*)&hc0)[cc];                 // static index
      unsigned w1 = ((const unsigned*)&hc1)[cc];
      const int sbase = (cc & 3) * 1024;               // short8 index of ring slot (16KB = 1024 short8)
      #pragma unroll
      for (int hh = 0; hh < 2; ++hh) {                 // h-scalar within word: lo then hi
        float2v h20, h21;
        h20[0] = h20[1] = bf2f((u16)(hh ? (w0 >> 16) : (w0 & 0xffffu)));
        h21[0] = h21[1] = bf2f((u16)(hh ? (w1 >> 16) : (w1 & 0xffffu)));
        #pragma unroll
        for (int tt = 0; tt < 4; ++tt) {               // kt = 8c + 4hh + tt
          short8_t b0 = sb8[sbase + (hh * 4 + tt) * 128 + lane];
          short8_t b1 = sb8[sbase + (hh * 4 + tt) * 128 + 64 + lane];
          short8_t a0 = scale8r(xra[tt], h20);
          short8_t a1 = scale8r(xrb[tt], h21);
          acc00 = __builtin_amdgcn_mfma_f32_32x32x16_bf16(a0, b0, acc00, 0, 0, 0);
          acc01 = __builtin_amdgcn_mfma_f32_32x32x16_bf16(a0, b1, acc01, 0, 0, 0);
          acc10 = __builtin_amdgcn_mfma_f32_32x32x16_bf16(a1, b0, acc10, 0, 0, 0);
          acc11 = __builtin_amdgcn_mfma_f32_32x32x16_bf16(a1, b1, acc11, 0, 0, 0);
        }
      }
      // counted handoff: my ds_reads done (free), my stage(c+1) retired; c+2/c+3 in flight
      asm volatile("s_waitcnt lgkmcnt(0)" ::: "memory");
      asm volatile("s_waitcnt vmcnt(8)" ::: "memory");
      __builtin_amdgcn_sched_barrier(0);
      __builtin_amdgcn_s_barrier();
    }
    hc0 = hn0; hc1 = hn1;
    if (g < 6) { hn0 = ha4[g + 2]; hn1 = hb4[g + 2]; }
  }

  // tail: chunk 32 = kt 256..259 (b2 bias rows), A = x exactly (hs=1.0), ring slot 0
  {
    float2v h2; h2[0] = 1.0f; h2[1] = 1.0f;
    #pragma unroll
    for (int tt = 0; tt < 4; ++tt) {
      short8_t b0 = sb8[tt * 128 + lane];
      short8_t b1 = sb8[tt * 128 + 64 + lane];
      short8_t a0 = scale8r(xra[tt], h2);
      short8_t a1 = scale8r(xrb[tt], h2);
      acc00 = __builtin_amdgcn_mfma_f32_32x32x16_bf16(a0, b0, acc00, 0, 0, 0);
      acc01 = __builtin_amdgcn_mfma_f32_32x32x16_bf16(a0, b1, acc01, 0, 0, 0);
      acc10 = __builtin_amdgcn_mfma_f32_32x32x16_bf16(a1, b0, acc10, 0, 0, 0);
      acc11 = __builtin_amdgcn_mfma_f32_32x32x16_bf16(a1, b1, acc11, 0, 0, 0);
    }
  }

  // epilogue: C/D layout col=lane&31, row=(reg&3)+8*(reg>>2)+4*q; bf16 stores, both tiles
  #pragma unroll
  for (int reg = 0; reg < 16; ++reg) {
    int row = (reg & 3) + 8 * (reg >> 2) + 4 * q;
    int e1 = e0 + wid * 64 + row;
    int e2 = e1 + 32;
    if (e1 < E) {
      msg[(size_t)e1 * 64 + ml]      = f2bf(acc00[reg]);
      msg[(size_t)e1 * 64 + 32 + ml] = f2bf(acc01[reg]);
    }
    if (e2 < E) {
      msg[(size_t)e2 * 64 + ml]      = f2bf(acc10[reg]);
      msg[(size_t)e2 * 64 + 32 + ml] = f2bf(acc11[reg]);
    }
  }
}

// ---------------- x_new = relu(x @ root + gather_mean(msg) + bias) — MFMA, fused ----------------
__global__ __launch_bounds__(256, 4) void update_kernel(
    const u16* __restrict__ Xig, const u16* __restrict__ Mgg, const int* __restrict__ cg,
    const int* __restrict__ elg, const u16* __restrict__ rpg, const float* __restrict__ bg,
    u16* __restrict__ Xog, int Ng, int nbg,
    const u16* __restrict__ Xil, const u16* __restrict__ Mgl, const int* __restrict__ cl,
    const int* __restrict__ ell, const u16* __restrict__ rpl, const float* __restrict__ bl,
    u16* __restrict__ Xol, int Nl)
{
  const int b = blockIdx.x;
  const u16 *Xin, *rootp, *msg; const float *bias; const int *cnt, *elist;
  u16* Xout; int N, n0;
  if (b < nbg) { Xin=Xig; msg=Mgg; cnt=cg; elist=elg; rootp=rpg; bias=bg; Xout=Xog; N=Ng; n0=b*128; }
  else         { Xin=Xil; msg=Mgl; cnt=cl; elist=ell; rootp=rpl; bias=bl; Xout=Xol; N=Nl; n0=(b-nbg)*128; }

  const int t = threadIdx.x;
  const int lane = t & 63;
  const int wid = t >> 6;
  const int ml = lane & 31;
  const int q  = lane >> 5;
  const int nbase = n0 + wid * 32;

  const int na = nbase + ml;
  const int nac = na < N ? na : N - 1;

  U8 xr[4];
  {
    const u16* xp = Xin + (size_t)nac * 64 + q * 8;
    #pragma unroll
    for (int s = 0; s < 4; ++s) xr[s].v = *(const uint4*)(xp + s * 16);
  }
  U8 rp[8];
  {
    const uint4* rpv = (const uint4*)rootp;
    #pragma unroll
    for (int i = 0; i < 8; ++i) rp[i].v = rpv[i * 64 + lane];
  }
  const float bias0 = bias[ml], bias1 = bias[32 + ml];

  float16_t acc0, acc1;
  #pragma unroll
  for (int i = 0; i < 16; ++i) { acc0[i] = 0.f; acc1[i] = 0.f; }
  #pragma unroll
  for (int kt = 0; kt < 4; ++kt) {
    acc0 = __builtin_amdgcn_mfma_f32_32x32x16_bf16(xr[kt].s, rp[kt * 2 + 0].s, acc0, 0, 0, 0);
    acc1 = __builtin_amdgcn_mfma_f32_32x32x16_bf16(xr[kt].s, rp[kt * 2 + 1].s, acc1, 0, 0, 0);
  }

  #pragma unroll
  for (int reg = 0; reg < 16; ++reg) {
    int row = (reg & 3) + 8 * (reg >> 2) + 4 * q;
    int nn = nbase + row;
    if (nn < N) {
      int c = cnt[nn];
      int cc = c < DEG_CAP ? c : DEG_CAP;
      const int* ep = elist + (size_t)nn * DEG_CAP;
      float a0 = 0.f, a1 = 0.f;
      int j = 0;
      for (; j + 4 <= cc; j += 4) {      // de-serialized: 4 elist + 8 msg loads in flight
        int e0i = ep[j], e1i = ep[j + 1], e2i = ep[j + 2], e3i = ep[j + 3];
        u16 m00 = msg[(size_t)e0i * 64 + ml], m01 = msg[(size_t)e0i * 64 + 32 + ml];
        u16 m10 = msg[(size_t)e1i * 64 + ml], m11 = msg[(size_t)e1i * 64 + 32 + ml];
        u16 m20 = msg[(size_t)e2i * 64 + ml], m21 = msg[(size_t)e2i * 64 + 32 + ml];
        u16 m30 = msg[(size_t)e3i * 64 + ml], m31 = msg[(size_t)e3i * 64 + 32 + ml];
        a0 += bf2f(m00) + bf2f(m10) + bf2f(m20) + bf2f(m30);
        a1 += bf2f(m01) + bf2f(m11) + bf2f(m21) + bf2f(m31);
      }
      for (; j < cc; ++j) {
        int e = ep[j];
        a0 += bf2f(msg[(size_t)e * 64 + ml]);
        a1 += bf2f(msg[(size_t)e * 64 + 32 + ml]);
      }
      float rc = (c > 1) ? (1.0f / (float)c) : 1.0f;
      float o0 = fmaxf(acc0[reg] + a0 * rc + bias0, 0.f);
      float o1 = fmaxf(acc1[reg] + a1 * rc + bias1, 0.f);
      Xout[(size_t)nn * 64 + ml]      = f2bf(o0);
      Xout[(size_t)nn * 64 + 32 + ml] = f2bf(o1);
    }
  }
}

// ---------------- fused pool: both branches in one launch (R8 atomics version) ----------------
__device__ __forceinline__ void pool_body(const u16* __restrict__ X, float* __restrict__ out64,
                                          int nchunks, int bid, int t)
{
  __shared__ float red[64];
  if (t < 64) red[t] = 0.f;
  __syncthreads();
  int gid = bid * 256 + t;
  float s[8];
  #pragma unroll
  for (int j = 0; j < 8; ++j) s[j] = 0.f;
  for (int i = gid; i < nchunks; i += 256 * 256) {
    uint4 v = ((const uint4*)X)[i];
    s[0] += bf2f((u16)(v.x & 0xffffu)); s[1] += bf2f((u16)(v.x >> 16));
    s[2] += bf2f((u16)(v.y & 0xffffu)); s[3] += bf2f((u16)(v.y >> 16));
    s[4] += bf2f((u16)(v.z & 0xffffu)); s[5] += bf2f((u16)(v.z >> 16));
    s[6] += bf2f((u16)(v.w & 0xffffu)); s[7] += bf2f((u16)(v.w >> 16));
  }
  int cg = (gid & 7) * 8;
  #pragma unroll
  for (int j = 0; j < 8; ++j) atomicAdd(red + cg + j, s[j]);
  __syncthreads();
  if (t < 64) atomicAdd(out64 + t, red[t]);
}

__global__ __launch_bounds__(256) void pool_kernel(
    const u16* __restrict__ Xg, float* __restrict__ og, int ncg,
    const u16* __restrict__ Xl, float* __restrict__ ol, int ncl)
{
  int b = blockIdx.x, t = threadIdx.x;
  if (b < 256) pool_body(Xg, og, ncg, b, t);
  else         pool_body(Xl, ol, ncl, b - 256, t);
}

// ---------------- head: parallel per-layer GEMV (R8 structure, prep folded into bott) ----------------
// gemv_bott gathers [pool_g | pool_l | adduct] inline — removes the prep_head dispatch.
// Partial-sum order identical to prep+gemv (16 strided partials, g-ascending) -> bit-identical.
__global__ __launch_bounds__(256) void gemv_bott_kernel(
    const float* __restrict__ pg, const float* __restrict__ pl, const float* __restrict__ adduct,
    const float* __restrict__ W, const float* __restrict__ b, float* __restrict__ out)
{
  __shared__ float red[16][17];
  int t = threadIdx.x;
  int ol = t & 15, ig = t >> 4;
  int o = blockIdx.x * 16 + ol;
  float s = 0.f;
  for (int i = ig; i < 131; i += 16) {
    float v = (i < 64) ? pg[i] : (i < 128 ? pl[i - 64] : adduct[i - 128]);
    s = fmaf(v, W[i * 384 + o], s);
  }
  red[ig][ol] = s;
  __syncthreads();
  if (t < 16) {
    int oo = blockIdx.x * 16 + t;
    float acc = b[oo];
    #pragma unroll
    for (int g = 0; g < 16; ++g) acc += red[g][t];
    out[oo] = fmaxf(acc, 0.f);
  }
}

__global__ __launch_bounds__(256) void gemv_relu_kernel(
    const float* __restrict__ in, const float* __restrict__ W, const float* __restrict__ b,
    float* __restrict__ out, int Ni, int No)
{
  __shared__ float red[16][17];
  int t = threadIdx.x;
  int ol = t & 15, ig = t >> 4;
  int o = blockIdx.x * 16 + ol;
  float s = 0.f;
  for (int i = ig; i < Ni; i += 16)
    s = fmaf(in[i], W[i * No + o], s);
  red[ig][ol] = s;
  __syncthreads();
  if (t < 16) {
    int oo = blockIdx.x * 16 + t;
    float acc = b[oo];
    #pragma unroll
    for (int g = 0; g < 16; ++g) acc += red[g][t];
    out[oo] = fmaxf(acc, 0.f);
  }
}

__global__ __launch_bounds__(384) void final_kernel(
    const float* __restrict__ u, const float* __restrict__ l2w, const float* __restrict__ l2b,
    float* __restrict__ out)
{
  __shared__ float wred[6];
  int t = threadIdx.x;
  float p = u[t] * l2w[t];
  #pragma unroll
  for (int off = 32; off > 0; off >>= 1) p += __shfl_down(p, off);
  if ((t & 63) == 0) wred[t >> 6] = p;
  __syncthreads();
  if (t == 0) {
    float s = l2b[0];
    #pragma unroll
    for (int i = 0; i < 6; ++i) s += wred[i];
    out[0] = s;
  }
}

extern "C" void kernel_launch(void* const* d_in, const int* in_sizes, int n_in,
                              void* d_out, int out_size, void* d_ws, size_t ws_size,
                              hipStream_t stream)
{
  const int NG = 30000, EG = 60000, NLG = 60000, ELG = 60000;

  const float* gx      = (const float*)d_in[0];
  const int*   g_ei    = (const int*)  d_in[1];
  const float* g_ea    = (const float*)d_in[2];
  const float* lgx     = (const float*)d_in[3];
  const int*   lg_ei   = (const int*)  d_in[4];
  const float* lg_ea   = (const float*)d_in[5];
  const float* adduct  = (const float*)d_in[6];
  const float* lin0_w  = (const float*)d_in[7];
  const float* lin0_b  = (const float*)d_in[8];
  const float* g_w1    = (const float*)d_in[9];
  const float* g_b1    = (const float*)d_in[10];
  const float* g_w2    = (const float*)d_in[11];
  const float* g_b2    = (const float*)d_in[12];
  const float* g_root  = (const float*)d_in[13];
  const float* g_bias  = (const float*)d_in[14];
  const float* l0lg_w  = (const float*)d_in[15];
  const float* l0lg_b  = (const float*)d_in[16];
  const float* lg_w1   = (const float*)d_in[17];
  const float* lg_b1   = (const float*)d_in[18];
  const float* lg_w2   = (const float*)d_in[19];
  const float* lg_b2   = (const float*)d_in[20];
  const float* lg_root = (const float*)d_in[21];
  const float* lg_bias = (const float*)d_in[22];
  const float* bott_w  = (const float*)d_in[23];
  const float* bott_b  = (const float*)d_in[24];
  const float* lin1_w  = (const float*)d_in[25];
  const float* lin1_b  = (const float*)d_in[26];
  const float* lin2_w  = (const float*)d_in[27];
  const float* lin2_b  = (const float*)d_in[28];

  char* p = (char*)d_ws;
  auto alloc = [&](size_t bytes) { char* r = p; p += (bytes + 255) & ~(size_t)255; return r; };
  u16*   xg_a   = (u16*)  alloc((size_t)NG  * 64 * 2);
  u16*   xg_b   = (u16*)  alloc((size_t)NG  * 64 * 2);
  u16*   xl_a   = (u16*)  alloc((size_t)NLG * 64 * 2);
  u16*   xl_b   = (u16*)  alloc((size_t)NLG * 64 * 2);
  u16*   h_g    = (u16*)  alloc((size_t)EG  * 64 * 2);
  u16*   h_l    = (u16*)  alloc((size_t)ELG * 64 * 2);
  u16*   bp_g   = (u16*)  alloc((size_t)NKT * 128 * 8 * 2 + 49152);  // slack: 16KB chunks stage up to chunk 34
  u16*   bp_l   = (u16*)  alloc((size_t)NKT * 128 * 8 * 2 + 49152);
  u16*   rp_g   = (u16*)  alloc(512 * 8 * 2);
  u16*   rp_l   = (u16*)  alloc(512 * 8 * 2);
  u16*   msg_g  = (u16*)  alloc((size_t)EG  * 64 * 2);   // bf16 msg
  u16*   msg_l  = (u16*)  alloc((size_t)ELG * 64 * 2);
  int*   cnt_g  = (int*)  alloc((size_t)NG  * 4);   // cnt_g/cnt_l adjacent: single zero-fill span
  int*   cnt_l  = (int*)  alloc((size_t)NLG * 4);
  int*   el_g   = (int*)  alloc((size_t)NG  * DEG_CAP * 4);
  int*   el_l   = (int*)  alloc((size_t)NLG * DEG_CAP * 4);
  float* pool_g = (float*)alloc(64 * 4);            // pools adjacent: single memset
  float* pool_l = (float*)alloc(64 * 4);
  float* h0     = (float*)alloc(384 * 4);
  float* h1     = (float*)alloc(384 * 4);

  // ---- setup (cnt zero-fill folded into affine_all) ----
  const int B0 = NG * 64 / 256, B1 = B0 + NLG * 64 / 256, B2 = B1 + EG * 64 / 256;
  const int B3 = B2 + ELG * 64 / 256;
  const int NZ = (int)(((size_t)((char*)cnt_l - (char*)cnt_g)) / 4) + NLG;  // span incl. align pad
  const int zb = (NZ + 255) / 256;
  affine_all_kernel<<<B3 + zb, 256, 0, stream>>>(
      gx, lin0_w, lin0_b, xg_a, lgx, l0lg_w, l0lg_b, xl_a,
      g_ea, g_w1, g_b1, h_g, lg_ea, lg_w1, lg_b1, h_l,
      B0, B1, B2, B3, NG, NLG, EG, ELG, cnt_g, NZ);
  pack_all_kernel<<<264, 256, 0, stream>>>(g_w2, g_b2, bp_g, lg_w2, lg_b2, bp_l,
                                           g_root, rp_g, lg_root, rp_l);
  const int nhg = (EG + 255) / 256, nhl = (ELG + 255) / 256;
  hist_kernel<<<nhg + nhl, 256, 0, stream>>>(g_ei, cnt_g, el_g, EG, nhg, lg_ei, cnt_l, el_l, ELG);

  // ---- fused 3-iteration loop (256 edges/block, 4 waves x 64 edges, 16KB-chunk LDS ring) ----
  const int nbg_m = (EG + 255) / 256, nbl_m = (ELG + 255) / 256;
  const int nbg_u = (NG + 127) / 128, nbl_u = (NLG + 127) / 128;
  u16 *xgc = xg_a, *xgn = xg_b, *xlc = xl_a, *xln = xl_b;
  for (int it = 0; it < 3; ++it) {
    msg_gemm_kernel<<<nbg_m + nbl_m, 256, 0, stream>>>(
        xgc, h_g, bp_g, g_ei, msg_g, EG, nbg_m,
        xlc, h_l, bp_l, lg_ei, msg_l, ELG);
    update_kernel<<<nbg_u + nbl_u, 256, 0, stream>>>(
        xgc, msg_g, cnt_g, el_g, rp_g, g_bias, xgn, NG, nbg_u,
        xlc, msg_l, cnt_l, el_l, rp_l, lg_bias, xln, NLG);
    u16* tmp = xgc; xgc = xgn; xgn = tmp;
    tmp = xlc; xlc = xln; xln = tmp;
  }

  hipMemsetAsync(pool_g, 0, (size_t)((char*)pool_l - (char*)pool_g) + 64 * 4, stream);
  pool_kernel<<<512, 256, 0, stream>>>(xgc, pool_g, NG * 8, xlc, pool_l, NLG * 8);

  gemv_bott_kernel<<<24, 256, 0, stream>>>(pool_g, pool_l, adduct, bott_w, bott_b, h0);
  float* ua = h0; float* ub = h1;
  for (int L = 0; L < 6; ++L) {
    gemv_relu_kernel<<<24, 256, 0, stream>>>(ua, lin1_w, lin1_b, ub, 384, 384);
    float* tmp = ua; ua = ub; ub = tmp;
  }
  final_kernel<<<1, 384, 0, stream>>>(ua, lin2_w, lin2_b, (float*)d_out);
}